// Round 7
// baseline (1058.352 us; speedup 1.0000x reference)
//
#include <hip/hip_runtime.h>
#include <cmath>

// ---------------------------------------------------------------------------
// ExpandLossLayer round 7: fully fused, label-gated.
// Per row (one per wave): read labels first ->
//   absent  class: only row max needed (no histogram/atomics/exp2)
//   present class: ONE score (bg if c==0 else fg) via wave-private 256-bin
//     packed histogram (count bits 21..31; value*1024 bits 0..20).
// Lane 0 converts to the loss contribution and does one deterministic
// fixed-point atomicAdd (contrib/B * 2^42 as u64) into d_ws; a 1-thread
// kernel converts to float.  d_ws[0] zeroed each call via hipMemsetAsync.
// ---------------------------------------------------------------------------

#define NBIN  256
#define BLOCK 256
#define WPB   4                    // waves (= rows) per block

constexpr int Pn = 1681;           // 41*41
constexpr int Bn = 4096;
constexpr int Cn = 21;
constexpr int Rn = Bn * Cn;        // 86016 rows

__global__ __launch_bounds__(BLOCK) void row_loss_kernel(
    const float* __restrict__ x, const int* __restrict__ labels,
    unsigned long long* __restrict__ acc,
    float l2q_fg, float invW_fg, float l2q_bg, float invW_bg)
{
    __shared__ unsigned int shist[WPB][NBIN];   // 4 KB

    const int t    = threadIdx.x;
    const int wave = t >> 6, lane = t & 63;
    const int row  = blockIdx.x * WPB + wave;
    const int b    = row / Cn;
    const int c    = row - b * Cn;
    const float* __restrict__ rp = x + (size_t)row * Pn;
    unsigned int* hist = shist[wave];

    // ---- labels for this batch (wave-uniform decision) ----
    int lab = (lane < Cn) ? labels[b * Cn + lane] : 0;
    const unsigned long long mask = __ballot(lab != 0);
    const bool present = (mask >> c) & 1ull;
    const int n_fg = __popcll(mask & 0x1FFFFEull);          // c in 1..20
    const int n_ab = __popcll(~mask & 0x1FFFFFull);         // 21 classes

    // ---- alignment split: head scalars | aligned float4 x nvec | tail ----
    const int head  = (4 - (row & 3)) & 3;       // 0..3 (fixed per wave)
    const int nvec  = (Pn - head) >> 2;          // 419 or 420
    const int ntail = Pn - head - (nvec << 2);   // 0..3
    const float4* __restrict__ rv = (const float4*)(rp + head);

    float vh = 0.0f, vt = 0.0f;
    if (lane < head)  vh = rp[lane];
    if (lane < ntail) vt = rp[head + (nvec << 2) + lane];
    float4 f[7];
#pragma unroll
    for (int j = 0; j < 7; ++j) {
        int i = lane + j * 64;
        if (i < nvec) f[j] = rv[i];
    }

    float vmax = fmaxf(vh, vt);   // inactive lanes hold 0; row values > 0
#pragma unroll
    for (int j = 0; j < 6; ++j) {
        float4 q = f[j];
        vmax = fmaxf(vmax, fmaxf(fmaxf(q.x, q.y), fmaxf(q.z, q.w)));
    }
    if (lane + 6 * 64 < nvec) {
        float4 q = f[6];
        vmax = fmaxf(vmax, fmaxf(fmaxf(q.x, q.y), fmaxf(q.z, q.w)));
    }

    float score = 0.0f;
    if (present) {
        // zero own region: one ds_write_b128 per lane
        ((uint4*)hist)[lane] = make_uint4(0u, 0u, 0u, 0u);

        auto proc = [&](float vv) {
            int k = (int)(vv * (float)NBIN);               // v < 1 -> k <= 255
            unsigned int pack = (1u << 21)
                | (unsigned int)fmaf(vv, 1024.0f, 0.5f);
            atomicAdd(&hist[k], pack);
        };
        if (lane < head)  proc(vh);
        if (lane < ntail) proc(vt);
#pragma unroll
        for (int j = 0; j < 6; ++j) {
            float4 q = f[j];
            proc(q.x); proc(q.y); proc(q.z); proc(q.w);
        }
        if (lane + 6 * 64 < nvec) {
            float4 q = f[6];
            proc(q.x); proc(q.y); proc(q.z); proc(q.w);
        }

        // decode own 4 bins: one ds_read_b128 (bins 4*lane .. 4*lane+3)
        uint4 pk = ((const uint4*)hist)[lane];
        unsigned int h0 = pk.x >> 21, h1 = pk.y >> 21,
                     h2 = pk.z >> 21, h3 = pk.w >> 21;
        const float sc = 1.0f / 1024.0f;
        float S0 = (float)(pk.x & 0x1FFFFFu) * sc;
        float S1 = (float)(pk.y & 0x1FFFFFu) * sc;
        float S2 = (float)(pk.z & 0x1FFFFFu) * sc;
        float S3 = (float)(pk.w & 0x1FFFFFu) * sc;
        unsigned int own = h0 + h1 + h2 + h3;

        unsigned int pre = own;
#pragma unroll
        for (int off = 1; off < 64; off <<= 1) {
            unsigned int n = __shfl_up(pre, off);
            if (lane >= off) pre += n;
        }
        float running = (float)(Pn - (int)pre);

        const float l2q  = (c == 0) ? l2q_bg  : l2q_fg;
        const float invW = (c == 0) ? invW_bg : invW_fg;
        float s = 0.0f;
        auto bin = [&](float S, unsigned int h) {
            float hf = (float)h;
            float r = running + 0.5f * (hf - 1.0f);
            s = fmaf(S, exp2f(r * l2q), s);
            running += hf;
        };
        bin(S3, h3); bin(S2, h2); bin(S1, h1); bin(S0, h0);
        score = s * invW;
    }

    // ---- wave reduction ----
#pragma unroll
    for (int off = 32; off > 0; off >>= 1) {
        score += __shfl_down(score, off);
        vmax = fmaxf(vmax, __shfl_down(vmax, off));
    }
    if (lane == 0) {
        float contrib;
        if (present)
            contrib = (c == 0) ? -logf(score) : -logf(score) / (float)n_fg;
        else
            contrib = -logf(vmax) / (float)n_ab;
        // contrib >= 0; scale by 1/Bn and 2^42 -> contrib * 2^30
        unsigned long long q =
            (unsigned long long)llrintf(contrib * 1073741824.0f);
        atomicAdd(acc, q);
    }
}

__global__ void final_kernel(const unsigned long long* __restrict__ acc,
                             float* __restrict__ out)
{
    if (threadIdx.x == 0)
        out[0] = (float)((double)(long long)acc[0] * (1.0 / 4398046511104.0));
}

extern "C" void kernel_launch(void* const* d_in, const int* in_sizes, int n_in,
                              void* d_out, int out_size, void* d_ws, size_t ws_size,
                              hipStream_t stream)
{
    const float* x      = (const float*)d_in[0];   // (B,C,41,41) f32
    const int*   labels = (const int*)d_in[1];     // (B,C) i32
    float* out = (float*)d_out;
    unsigned long long* acc = (unsigned long long*)d_ws;

    const double lnq_fg = std::log(0.996);
    const double lnq_bg = std::log(0.999);
    const double Wfg = (1.0 - std::exp(lnq_fg * (double)Pn)) / (1.0 - 0.996);
    const double Wbg = (1.0 - std::exp(lnq_bg * (double)Pn)) / (1.0 - 0.999);
    const float l2q_fg  = (float)(lnq_fg / M_LN2);
    const float l2q_bg  = (float)(lnq_bg / M_LN2);
    const float invW_fg = (float)(1.0 / Wfg);
    const float invW_bg = (float)(1.0 / Wbg);

    hipMemsetAsync(acc, 0, sizeof(unsigned long long), stream);
    row_loss_kernel<<<Rn / WPB, BLOCK, 0, stream>>>(x, labels, acc,
                                                    l2q_fg, invW_fg, l2q_bg, invW_bg);
    final_kernel<<<1, 64, 0, stream>>>(acc, out);
}

// Round 8
// 105.126 us; speedup vs baseline: 10.0675x; 10.0675x over previous
//
#include <hip/hip_runtime.h>
#include <cmath>

// ---------------------------------------------------------------------------
// ExpandLossLayer round 8: label-gated fused row kernel (r7) WITHOUT the
// contended global atomic (r7's 1 ms failure: 86k device atomics to one
// cacheline).  Lane 0 stores its row's loss contribution to ws[row]; a
// fixed-shape tree reduction (84 blocks x 256 thr x 4 elem) + final kernel
// produce the scalar deterministically.  No global atomics anywhere.
// Per row (one per wave): read labels first ->
//   absent  class: only row max needed (no histogram/atomics/exp2)
//   present class: ONE score (bg if c==0 else fg) via wave-private 256-bin
//     packed histogram (count bits 21..31; value*1024 bits 0..20).
// ---------------------------------------------------------------------------

#define NBIN  256
#define BLOCK 256
#define WPB   4                    // waves (= rows) per block

constexpr int Pn = 1681;           // 41*41
constexpr int Bn = 4096;
constexpr int Cn = 21;
constexpr int Rn = Bn * Cn;        // 86016 rows

#define RBLOCKS 84                 // Rn / (256*4) = 84 exactly
#define RTHREADS 256

__global__ __launch_bounds__(BLOCK) void row_loss_kernel(
    const float* __restrict__ x, const int* __restrict__ labels,
    float* __restrict__ contrib,
    float l2q_fg, float invW_fg, float l2q_bg, float invW_bg)
{
    __shared__ unsigned int shist[WPB][NBIN];   // 4 KB

    const int t    = threadIdx.x;
    const int wave = t >> 6, lane = t & 63;
    const int row  = blockIdx.x * WPB + wave;
    const int b    = row / Cn;
    const int c    = row - b * Cn;
    const float* __restrict__ rp = x + (size_t)row * Pn;
    unsigned int* hist = shist[wave];

    // ---- labels for this batch (wave-uniform decision) ----
    int lab = (lane < Cn) ? labels[b * Cn + lane] : 0;
    const unsigned long long mask = __ballot(lab != 0);
    const bool present = (mask >> c) & 1ull;
    const int n_fg = __popcll(mask & 0x1FFFFEull);          // c in 1..20
    const int n_ab = __popcll(~mask & 0x1FFFFFull);         // 21 classes

    // ---- alignment split: head scalars | aligned float4 x nvec | tail ----
    const int head  = (4 - (row & 3)) & 3;       // 0..3 (fixed per wave)
    const int nvec  = (Pn - head) >> 2;          // 419 or 420
    const int ntail = Pn - head - (nvec << 2);   // 0..3
    const float4* __restrict__ rv = (const float4*)(rp + head);

    float vh = 0.0f, vt = 0.0f;
    if (lane < head)  vh = rp[lane];
    if (lane < ntail) vt = rp[head + (nvec << 2) + lane];
    float4 f[7];
#pragma unroll
    for (int j = 0; j < 7; ++j) {
        int i = lane + j * 64;
        if (i < nvec) f[j] = rv[i];
    }

    float vmax = fmaxf(vh, vt);   // inactive lanes hold 0; row values > 0
#pragma unroll
    for (int j = 0; j < 6; ++j) {
        float4 q = f[j];
        vmax = fmaxf(vmax, fmaxf(fmaxf(q.x, q.y), fmaxf(q.z, q.w)));
    }
    if (lane + 6 * 64 < nvec) {
        float4 q = f[6];
        vmax = fmaxf(vmax, fmaxf(fmaxf(q.x, q.y), fmaxf(q.z, q.w)));
    }

    float score = 0.0f;
    if (present) {
        // zero own region: one ds_write_b128 per lane
        ((uint4*)hist)[lane] = make_uint4(0u, 0u, 0u, 0u);

        auto proc = [&](float vv) {
            int k = (int)(vv * (float)NBIN);               // v < 1 -> k <= 255
            unsigned int pack = (1u << 21)
                | (unsigned int)fmaf(vv, 1024.0f, 0.5f);
            atomicAdd(&hist[k], pack);
        };
        if (lane < head)  proc(vh);
        if (lane < ntail) proc(vt);
#pragma unroll
        for (int j = 0; j < 6; ++j) {
            float4 q = f[j];
            proc(q.x); proc(q.y); proc(q.z); proc(q.w);
        }
        if (lane + 6 * 64 < nvec) {
            float4 q = f[6];
            proc(q.x); proc(q.y); proc(q.z); proc(q.w);
        }

        // decode own 4 bins: one ds_read_b128 (bins 4*lane .. 4*lane+3)
        uint4 pk = ((const uint4*)hist)[lane];
        unsigned int h0 = pk.x >> 21, h1 = pk.y >> 21,
                     h2 = pk.z >> 21, h3 = pk.w >> 21;
        const float sc = 1.0f / 1024.0f;
        float S0 = (float)(pk.x & 0x1FFFFFu) * sc;
        float S1 = (float)(pk.y & 0x1FFFFFu) * sc;
        float S2 = (float)(pk.z & 0x1FFFFFu) * sc;
        float S3 = (float)(pk.w & 0x1FFFFFu) * sc;
        unsigned int own = h0 + h1 + h2 + h3;

        unsigned int pre = own;
#pragma unroll
        for (int off = 1; off < 64; off <<= 1) {
            unsigned int n = __shfl_up(pre, off);
            if (lane >= off) pre += n;
        }
        float running = (float)(Pn - (int)pre);

        const float l2q  = (c == 0) ? l2q_bg  : l2q_fg;
        const float invW = (c == 0) ? invW_bg : invW_fg;
        float s = 0.0f;
        auto bin = [&](float S, unsigned int h) {
            float hf = (float)h;
            float r = running + 0.5f * (hf - 1.0f);
            s = fmaf(S, exp2f(r * l2q), s);
            running += hf;
        };
        bin(S3, h3); bin(S2, h2); bin(S1, h1); bin(S0, h0);
        score = s * invW;
    }

    // ---- wave reduction ----
#pragma unroll
    for (int off = 32; off > 0; off >>= 1) {
        score += __shfl_down(score, off);
        vmax = fmaxf(vmax, __shfl_down(vmax, off));
    }
    if (lane == 0) {
        float v;
        if (present)
            v = (c == 0) ? -logf(score) : -logf(score) / (float)n_fg;
        else
            v = -logf(vmax) / (float)n_ab;
        contrib[row] = v;
    }
}

__global__ __launch_bounds__(RTHREADS) void reduce_kernel(
    const float* __restrict__ contrib, float* __restrict__ partial)
{
    const int tid = blockIdx.x * RTHREADS + threadIdx.x;   // 0..21503
    float s = 0.0f;
#pragma unroll
    for (int k = 0; k < 4; ++k) s += contrib[tid + k * (RBLOCKS * RTHREADS)];
#pragma unroll
    for (int off = 32; off > 0; off >>= 1) s += __shfl_down(s, off);
    __shared__ float sred[RTHREADS / 64];
    const int wave = threadIdx.x >> 6, lane = threadIdx.x & 63;
    if (lane == 0) sred[wave] = s;
    __syncthreads();
    if (threadIdx.x == 0) {
        float t = 0.0f;
        for (int w = 0; w < RTHREADS / 64; ++w) t += sred[w];
        partial[blockIdx.x] = t;
    }
}

__global__ void final_kernel(const float* __restrict__ partial,
                             float* __restrict__ out)
{
    if (threadIdx.x == 0) {
        float s = 0.0f;
        for (int i = 0; i < RBLOCKS; ++i) s += partial[i];
        out[0] = s / (float)Bn;
    }
}

extern "C" void kernel_launch(void* const* d_in, const int* in_sizes, int n_in,
                              void* d_out, int out_size, void* d_ws, size_t ws_size,
                              hipStream_t stream)
{
    const float* x      = (const float*)d_in[0];   // (B,C,41,41) f32
    const int*   labels = (const int*)d_in[1];     // (B,C) i32
    float* out = (float*)d_out;

    float* contrib = (float*)d_ws;        // Rn floats
    float* partial = contrib + Rn;        // RBLOCKS floats

    const double lnq_fg = std::log(0.996);
    const double lnq_bg = std::log(0.999);
    const double Wfg = (1.0 - std::exp(lnq_fg * (double)Pn)) / (1.0 - 0.996);
    const double Wbg = (1.0 - std::exp(lnq_bg * (double)Pn)) / (1.0 - 0.999);
    const float l2q_fg  = (float)(lnq_fg / M_LN2);
    const float l2q_bg  = (float)(lnq_bg / M_LN2);
    const float invW_fg = (float)(1.0 / Wfg);
    const float invW_bg = (float)(1.0 / Wbg);

    row_loss_kernel<<<Rn / WPB, BLOCK, 0, stream>>>(x, labels, contrib,
                                                    l2q_fg, invW_fg, l2q_bg, invW_bg);
    reduce_kernel<<<RBLOCKS, RTHREADS, 0, stream>>>(contrib, partial);
    final_kernel<<<1, 64, 0, stream>>>(partial, out);
}